// Round 2
// baseline (6275.850 us; speedup 1.0000x reference)
//
#include <hip/hip_runtime.h>
#include <math.h>

#define Hh 256
#define Ww 256
#define HW 65536

typedef _Float16 h16;

// ---------------- conv3x3 (x -> h_pre fp16) + instance-norm partial sums ----------------
__global__ __launch_bounds__(256) void k_conv3(const float* __restrict__ x,
    const float* __restrict__ wconv, h16* __restrict__ hpre,
    float* __restrict__ ssum, float* __restrict__ ssqs) {
  const int tile = blockIdx.x, ocg = blockIdx.y, b = blockIdx.z;
  const int ty0 = (tile >> 3) << 5, tx0 = (tile & 7) << 5;
  __shared__ float sIn[34 * 34];
  __shared__ float sW[72];
  const int tid = threadIdx.x;
  const int tx = tid & 31, tyq = tid >> 5;
  float acc[8][4];
#pragma unroll
  for (int o = 0; o < 8; o++)
#pragma unroll
    for (int r = 0; r < 4; r++) acc[o][r] = 0.f;
#pragma unroll 1
  for (int ic = 0; ic < 64; ++ic) {
    __syncthreads();
    const float* xs = x + ((size_t)(b * 64 + ic)) * HW;
    for (int i = tid; i < 34 * 34; i += 256) {
      int ly = i / 34, lx = i - ly * 34;
      int gy = ty0 + ly - 1, gx = tx0 + lx - 1;
      float v = 0.f;
      if ((unsigned)gy < 256u && (unsigned)gx < 256u) v = xs[gy * 256 + gx];
      sIn[i] = v;
    }
    if (tid < 72) sW[tid] = wconv[((size_t)(ocg * 8 + tid / 9) * 64 + ic) * 9 + (tid % 9)];
    __syncthreads();
#pragma unroll
    for (int k = 0; k < 9; k++) {
      const int ki = k / 3, kj = k - ki * 3;
      float wv[8];
#pragma unroll
      for (int o = 0; o < 8; o++) wv[o] = sW[o * 9 + k];
#pragma unroll
      for (int r = 0; r < 4; r++) {
        float v = sIn[(tyq * 4 + r + ki) * 34 + tx + kj];
#pragma unroll
        for (int o = 0; o < 8; o++) acc[o][r] = fmaf(wv[o], v, acc[o][r]);
      }
    }
  }
#pragma unroll
  for (int o = 0; o < 8; o++) {
    float s = 0.f, s2 = 0.f;
#pragma unroll
    for (int r = 0; r < 4; r++) { float v = acc[o][r]; s += v; s2 += v * v; }
    for (int d = 32; d > 0; d >>= 1) { s += __shfl_down(s, d); s2 += __shfl_down(s2, d); }
    if ((tid & 63) == 0) {
      atomicAdd(&ssum[b * 64 + ocg * 8 + o], s);
      atomicAdd(&ssqs[b * 64 + ocg * 8 + o], s2);
    }
    size_t base = ((size_t)(b * 64 + ocg * 8 + o)) * HW;
#pragma unroll
    for (int r = 0; r < 4; r++)
      hpre[base + (size_t)(ty0 + tyq * 4 + r) * Ww + tx0 + tx] = (h16)acc[o][r];
  }
}

// ---------------- finalize instance-norm stats ----------------
__global__ void k_stats(const float* __restrict__ ssum, const float* __restrict__ ssqs,
                        float* __restrict__ mean, float* __restrict__ rs) {
  int i = threadIdx.x;
  float m = ssum[i] * (1.f / 65536.f);
  float v = ssqs[i] * (1.f / 65536.f) - m * m;
  mean[i] = m;
  rs[i] = rsqrtf(v + 1e-5f);
}

// ---------------- IN-normalize + 1x1 (p1) + exact GELU -> u (fp16) ----------------
__global__ __launch_bounds__(256) void k_pw1(const h16* __restrict__ hpre,
    const float* __restrict__ mean, const float* __restrict__ rs,
    const float* __restrict__ w, const float* __restrict__ bias, h16* __restrict__ u) {
  const int chunk = blockIdx.x, b = blockIdx.y;
  const int px0 = chunk << 6;
  __shared__ __align__(16) float sIn[4096];
  __shared__ __align__(16) float sW[4096];
  const int tid = threadIdx.x;
  for (int i = tid; i < 4096; i += 256) {
    int ch = i >> 6, p = i & 63;
    float v = (float)hpre[((size_t)(b * 64 + ch)) * HW + px0 + p];
    sIn[i] = (v - mean[b * 64 + ch]) * rs[b * 64 + ch];
  }
  for (int i = tid; i < 4096; i += 256) { int ic = i >> 6, oc = i & 63; sW[i] = w[oc * 64 + ic]; }
  __syncthreads();
  const int p = tid & 63, ocg = tid >> 6;
  float acc[16];
#pragma unroll
  for (int j = 0; j < 16; j++) acc[j] = 0.f;
#pragma unroll 1
  for (int ic = 0; ic < 64; ++ic) {
    float v = sIn[(ic << 6) + p];
    const float4* wp = (const float4*)(sW + (ic << 6) + (ocg << 4));
    float4 w0 = wp[0], w1 = wp[1], w2 = wp[2], w3 = wp[3];
    acc[0] = fmaf(w0.x, v, acc[0]);  acc[1] = fmaf(w0.y, v, acc[1]);
    acc[2] = fmaf(w0.z, v, acc[2]);  acc[3] = fmaf(w0.w, v, acc[3]);
    acc[4] = fmaf(w1.x, v, acc[4]);  acc[5] = fmaf(w1.y, v, acc[5]);
    acc[6] = fmaf(w1.z, v, acc[6]);  acc[7] = fmaf(w1.w, v, acc[7]);
    acc[8] = fmaf(w2.x, v, acc[8]);  acc[9] = fmaf(w2.y, v, acc[9]);
    acc[10] = fmaf(w2.z, v, acc[10]); acc[11] = fmaf(w2.w, v, acc[11]);
    acc[12] = fmaf(w3.x, v, acc[12]); acc[13] = fmaf(w3.y, v, acc[13]);
    acc[14] = fmaf(w3.z, v, acc[14]); acc[15] = fmaf(w3.w, v, acc[15]);
  }
#pragma unroll
  for (int j = 0; j < 16; j++) {
    int oc = (ocg << 4) + j;
    float t = acc[j] + bias[oc];
    float g = 0.5f * t * (1.f + erff(t * 0.70710678f));
    u[((size_t)(b * 64 + oc)) * HW + px0 + p] = (h16)g;
  }
}

// ---------------- conv5x5 (u -> off0 fp16), Cout=50, pad=2 ----------------
__global__ __launch_bounds__(256) void k_conv5(const h16* __restrict__ u,
    const float* __restrict__ w5, const float* __restrict__ b5, h16* __restrict__ off0) {
  const int tile = blockIdx.x, ocg = blockIdx.y, b = blockIdx.z;
  const int ty0 = (tile >> 3) << 5, tx0 = (tile & 7) << 5;
  __shared__ __align__(16) float sIn[36 * 36];
  __shared__ __align__(16) float sW[25 * 12];
  const int tid = threadIdx.x, tx = tid & 31, tyq = tid >> 5;
  float acc[10][4];
#pragma unroll
  for (int o = 0; o < 10; o++)
#pragma unroll
    for (int r = 0; r < 4; r++) acc[o][r] = 0.f;
#pragma unroll 1
  for (int ic = 0; ic < 64; ++ic) {
    __syncthreads();
    const h16* us = u + ((size_t)(b * 64 + ic)) * HW;
    for (int i = tid; i < 36 * 36; i += 256) {
      int ly = i / 36, lx = i - ly * 36;
      int gy = ty0 + ly - 2, gx = tx0 + lx - 2;
      float v = 0.f;
      if ((unsigned)gy < 256u && (unsigned)gx < 256u) v = (float)us[gy * 256 + gx];
      sIn[i] = v;
    }
    for (int i = tid; i < 300; i += 256) {
      int k = i / 12, o = i - k * 12;
      sW[i] = (o < 10) ? w5[((size_t)(ocg * 10 + o) * 64 + ic) * 25 + k] : 0.f;
    }
    __syncthreads();
    int ki = 0, kj = 0;
#pragma unroll 1
    for (int k = 0; k < 25; k++) {
      const float4* wp = (const float4*)(sW + k * 12);
      float4 wa = wp[0], wb = wp[1], wc = wp[2];
      float wv[10] = {wa.x, wa.y, wa.z, wa.w, wb.x, wb.y, wb.z, wb.w, wc.x, wc.y};
#pragma unroll
      for (int r = 0; r < 4; r++) {
        float v = sIn[(tyq * 4 + r + ki) * 36 + tx + kj];
#pragma unroll
        for (int o = 0; o < 10; o++) acc[o][r] = fmaf(wv[o], v, acc[o][r]);
      }
      kj++; if (kj == 5) { kj = 0; ki++; }
    }
  }
#pragma unroll
  for (int o = 0; o < 10; o++) {
    float bb = b5[ocg * 10 + o];
    size_t base = ((size_t)(b * 50 + ocg * 10 + o)) * HW;
#pragma unroll
    for (int r = 0; r < 4; r++)
      off0[base + (size_t)(ty0 + tyq * 4 + r) * Ww + tx0 + tx] = (h16)(acc[o][r] + bb);
  }
}

// ---------------- conv7x7 dil=3 (a1 -> offs fp16), Cout=98, pad=9 ----------------
__global__ __launch_bounds__(256) void k_conv7(const h16* __restrict__ a1,
    const float* __restrict__ w7, const float* __restrict__ b7, h16* __restrict__ offs) {
  const int tile = blockIdx.x, ocg = blockIdx.y, b = blockIdx.z;
  const int ty0 = (tile >> 3) << 5, tx0 = (tile & 7) << 5;
  __shared__ __align__(16) float sIn[50 * 50];
  __shared__ __align__(16) float sW[49 * 16];
  const int tid = threadIdx.x, tx = tid & 31, tyq = tid >> 5;
  float acc[14][4];
#pragma unroll
  for (int o = 0; o < 14; o++)
#pragma unroll
    for (int r = 0; r < 4; r++) acc[o][r] = 0.f;
#pragma unroll 1
  for (int ic = 0; ic < 64; ++ic) {
    __syncthreads();
    const h16* as = a1 + ((size_t)(b * 64 + ic)) * HW;
    for (int i = tid; i < 50 * 50; i += 256) {
      int ly = i / 50, lx = i - ly * 50;
      int gy = ty0 + ly - 9, gx = tx0 + lx - 9;
      float v = 0.f;
      if ((unsigned)gy < 256u && (unsigned)gx < 256u) v = (float)as[gy * 256 + gx];
      sIn[i] = v;
    }
    for (int i = tid; i < 49 * 16; i += 256) {
      int k = i >> 4, o = i & 15;
      sW[i] = (o < 14) ? w7[((size_t)(ocg * 14 + o) * 64 + ic) * 49 + k] : 0.f;
    }
    __syncthreads();
    int ki = 0, kj = 0;
#pragma unroll 1
    for (int k = 0; k < 49; k++) {
      const float4* wp = (const float4*)(sW + (k << 4));
      float4 wa = wp[0], wb = wp[1], wc = wp[2], wd = wp[3];
      float wv[14] = {wa.x, wa.y, wa.z, wa.w, wb.x, wb.y, wb.z, wb.w,
                      wc.x, wc.y, wc.z, wc.w, wd.x, wd.y};
#pragma unroll
      for (int r = 0; r < 4; r++) {
        float v = sIn[(tyq * 4 + r + 3 * ki) * 50 + tx + 3 * kj];
#pragma unroll
        for (int o = 0; o < 14; o++) acc[o][r] = fmaf(wv[o], v, acc[o][r]);
      }
      kj++; if (kj == 7) { kj = 0; ki++; }
    }
  }
#pragma unroll
  for (int o = 0; o < 14; o++) {
    float bb = b7[ocg * 14 + o];
    size_t base = ((size_t)(b * 98 + ocg * 14 + o)) * HW;
#pragma unroll
    for (int r = 0; r < 4; r++)
      offs[base + (size_t)(ty0 + tyq * 4 + r) * Ww + tx0 + tx] = (h16)(acc[o][r] + bb);
  }
}

// ---------------- deformable depthwise conv (lane = pixel) ----------------
template <int KH, int KW, int PAD, int DIL, int NOFF, typename OutT>
__global__ __launch_bounds__(256) void k_dwdeform(const h16* __restrict__ inp,
    const h16* __restrict__ off, const float* __restrict__ wdw, OutT* __restrict__ out) {
  const int b = blockIdx.y, y = blockIdx.x, x = threadIdx.x;
  const h16* ib = inp + (size_t)b * 64 * HW;
  const size_t offb = (size_t)b * NOFF * HW + (size_t)y * Ww + x;
  const size_t pix = (size_t)y * Ww + x;
#pragma unroll 1
  for (int cc = 0; cc < 4; ++cc) {
    float acc[16];
#pragma unroll
    for (int j = 0; j < 16; j++) acc[j] = 0.f;
    int ki = 0, kj = 0;
#pragma unroll 1
    for (int k = 0; k < KH * KW; k++) {
      float dy = (float)off[offb + (size_t)(2 * k) * HW];
      float dx = (float)off[offb + (size_t)(2 * k + 1) * HW];
      float py = (float)(y - PAD + DIL * ki) + dy;
      float px = (float)(x - PAD + DIL * kj) + dx;
      float y0f = floorf(py), x0f = floorf(px);
      float fy = py - y0f, fx = px - x0f;
      int iy0 = (int)y0f, ix0 = (int)x0f;
      bool vy0 = (iy0 >= 0) && (iy0 <= 255), vy1 = (iy0 >= -1) && (iy0 <= 254);
      bool vx0 = (ix0 >= 0) && (ix0 <= 255), vx1 = (ix0 >= -1) && (ix0 <= 254);
      float w00 = (1.f - fy) * (1.f - fx) * ((vy0 && vx0) ? 1.f : 0.f);
      float w01 = (1.f - fy) * fx * ((vy0 && vx1) ? 1.f : 0.f);
      float w10 = fy * (1.f - fx) * ((vy1 && vx0) ? 1.f : 0.f);
      float w11 = fy * fx * ((vy1 && vx1) ? 1.f : 0.f);
      int cy0 = min(max(iy0, 0), 255), cy1 = min(max(iy0 + 1, 0), 255);
      int cx0 = min(max(ix0, 0), 255), cx1 = min(max(ix0 + 1, 0), 255);
      int p00 = cy0 * Ww + cx0, p01 = cy0 * Ww + cx1;
      int p10 = cy1 * Ww + cx0, p11 = cy1 * Ww + cx1;
#pragma unroll
      for (int j = 0; j < 16; j++) {
        const h16* uc = ib + (size_t)(cc * 16 + j) * HW;
        float s = w00 * (float)uc[p00] + w01 * (float)uc[p01]
                + w10 * (float)uc[p10] + w11 * (float)uc[p11];
        acc[j] = fmaf(s, wdw[(cc * 16 + j) * (KH * KW) + k], acc[j]);
      }
      kj++; if (kj == KW) { kj = 0; ki++; }
    }
#pragma unroll
    for (int j = 0; j < 16; j++)
      out[(size_t)(b * 64 + cc * 16 + j) * HW + pix] = (OutT)acc[j];
  }
}

// ---------------- 1x1 (g1): a2(fp32, in d_out) -> a3 (fp16) ----------------
__global__ __launch_bounds__(256) void k_g1(const float* __restrict__ a2,
    const float* __restrict__ w, const float* __restrict__ bias, h16* __restrict__ a3) {
  const int chunk = blockIdx.x, b = blockIdx.y;
  const int px0 = chunk << 6;
  __shared__ __align__(16) float sIn[4096];
  __shared__ __align__(16) float sW[4096];
  const int tid = threadIdx.x;
  for (int i = tid; i < 4096; i += 256) {
    int ch = i >> 6, p = i & 63;
    sIn[i] = a2[((size_t)(b * 64 + ch)) * HW + px0 + p];
  }
  for (int i = tid; i < 4096; i += 256) { int ic = i >> 6, oc = i & 63; sW[i] = w[oc * 64 + ic]; }
  __syncthreads();
  const int p = tid & 63, ocg = tid >> 6;
  float acc[16];
#pragma unroll
  for (int j = 0; j < 16; j++) acc[j] = 0.f;
#pragma unroll 1
  for (int ic = 0; ic < 64; ++ic) {
    float v = sIn[(ic << 6) + p];
    const float4* wp = (const float4*)(sW + (ic << 6) + (ocg << 4));
    float4 w0 = wp[0], w1 = wp[1], w2 = wp[2], w3 = wp[3];
    acc[0] = fmaf(w0.x, v, acc[0]);  acc[1] = fmaf(w0.y, v, acc[1]);
    acc[2] = fmaf(w0.z, v, acc[2]);  acc[3] = fmaf(w0.w, v, acc[3]);
    acc[4] = fmaf(w1.x, v, acc[4]);  acc[5] = fmaf(w1.y, v, acc[5]);
    acc[6] = fmaf(w1.z, v, acc[6]);  acc[7] = fmaf(w1.w, v, acc[7]);
    acc[8] = fmaf(w2.x, v, acc[8]);  acc[9] = fmaf(w2.y, v, acc[9]);
    acc[10] = fmaf(w2.z, v, acc[10]); acc[11] = fmaf(w2.w, v, acc[11]);
    acc[12] = fmaf(w3.x, v, acc[12]); acc[13] = fmaf(w3.y, v, acc[13]);
    acc[14] = fmaf(w3.z, v, acc[14]); acc[15] = fmaf(w3.w, v, acc[15]);
  }
#pragma unroll
  for (int j = 0; j < 16; j++) {
    int oc = (ocg << 4) + j;
    a3[((size_t)(b * 64 + oc)) * HW + px0 + p] = (h16)(acc[j] + bias[oc]);
  }
}

// ---------------- final: t=u*a3; 1x1 (p2); + IN(h); LeakyReLU ----------------
__global__ __launch_bounds__(256) void k_final(const h16* __restrict__ u,
    const h16* __restrict__ a3, const h16* __restrict__ hpre,
    const float* __restrict__ mean, const float* __restrict__ rs,
    const float* __restrict__ w, const float* __restrict__ bias, float* __restrict__ out) {
  const int chunk = blockIdx.x, b = blockIdx.y;
  const int px0 = chunk << 6;
  __shared__ __align__(16) float sIn[4096];
  __shared__ __align__(16) float sW[4096];
  const int tid = threadIdx.x;
  for (int i = tid; i < 4096; i += 256) {
    int ch = i >> 6, p = i & 63;
    size_t idx = ((size_t)(b * 64 + ch)) * HW + px0 + p;
    sIn[i] = (float)u[idx] * (float)a3[idx];
  }
  for (int i = tid; i < 4096; i += 256) { int ic = i >> 6, oc = i & 63; sW[i] = w[oc * 64 + ic]; }
  __syncthreads();
  const int p = tid & 63, ocg = tid >> 6;
  float acc[16];
#pragma unroll
  for (int j = 0; j < 16; j++) acc[j] = 0.f;
#pragma unroll 1
  for (int ic = 0; ic < 64; ++ic) {
    float v = sIn[(ic << 6) + p];
    const float4* wp = (const float4*)(sW + (ic << 6) + (ocg << 4));
    float4 w0 = wp[0], w1 = wp[1], w2 = wp[2], w3 = wp[3];
    acc[0] = fmaf(w0.x, v, acc[0]);  acc[1] = fmaf(w0.y, v, acc[1]);
    acc[2] = fmaf(w0.z, v, acc[2]);  acc[3] = fmaf(w0.w, v, acc[3]);
    acc[4] = fmaf(w1.x, v, acc[4]);  acc[5] = fmaf(w1.y, v, acc[5]);
    acc[6] = fmaf(w1.z, v, acc[6]);  acc[7] = fmaf(w1.w, v, acc[7]);
    acc[8] = fmaf(w2.x, v, acc[8]);  acc[9] = fmaf(w2.y, v, acc[9]);
    acc[10] = fmaf(w2.z, v, acc[10]); acc[11] = fmaf(w2.w, v, acc[11]);
    acc[12] = fmaf(w3.x, v, acc[12]); acc[13] = fmaf(w3.y, v, acc[13]);
    acc[14] = fmaf(w3.z, v, acc[14]); acc[15] = fmaf(w3.w, v, acc[15]);
  }
#pragma unroll
  for (int j = 0; j < 16; j++) {
    int oc = (ocg << 4) + j;
    size_t idx = ((size_t)(b * 64 + oc)) * HW + px0 + p;
    float hn = ((float)hpre[idx] - mean[b * 64 + oc]) * rs[b * 64 + oc];
    float t = acc[j] + bias[oc] + hn;
    out[idx] = (t >= 0.f) ? t : 0.2f * t;
  }
}

extern "C" void kernel_launch(void* const* d_in, const int* in_sizes, int n_in,
                              void* d_out, int out_size, void* d_ws, size_t ws_size,
                              hipStream_t stream) {
  const float* x      = (const float*)d_in[0];
  const float* conv_w = (const float*)d_in[1];
  const float* p1_w   = (const float*)d_in[2];
  const float* p1_b   = (const float*)d_in[3];
  const float* off0_w = (const float*)d_in[4];
  const float* off0_b = (const float*)d_in[5];
  const float* dw0_w  = (const float*)d_in[6];
  const float* offs_w = (const float*)d_in[7];
  const float* offs_b = (const float*)d_in[8];
  const float* dws_w  = (const float*)d_in[9];
  const float* g1_w   = (const float*)d_in[10];
  const float* g1_b   = (const float*)d_in[11];
  const float* p2_w   = (const float*)d_in[12];
  const float* p2_b   = (const float*)d_in[13];

  // Workspace layout (fp16 intermediates): total ~145 MiB
  float* ssum = (float*)d_ws;        // 256
  float* ssqs = ssum + 256;          // 256
  float* mean = ssum + 512;          // 256
  float* rs   = ssum + 768;          // 256
  h16* hpre = (h16*)((char*)d_ws + 4096);            // 16,777,216 h16 = 32 MiB
  h16* u    = hpre + (size_t)16777216;               // 32 MiB
  h16* a1   = u + (size_t)16777216;                  // 32 MiB
  h16* offs = a1 + (size_t)16777216;                 // 25,690,112 h16 = 49 MiB
  h16* off0 = offs;                                  // first 50ch region, consumed pre-conv7
  h16* a3   = a1;                                    // a1 dead after deform7
  float* a2 = (float*)d_out;                         // d_out as scratch for a2 (fp32)

  hipMemsetAsync(ssum, 0, 512 * sizeof(float), stream);

  k_conv3<<<dim3(64, 8, 4), 256, 0, stream>>>(x, conv_w, hpre, ssum, ssqs);
  k_stats<<<1, 256, 0, stream>>>(ssum, ssqs, mean, rs);
  k_pw1<<<dim3(1024, 4), 256, 0, stream>>>(hpre, mean, rs, p1_w, p1_b, u);
  k_conv5<<<dim3(64, 5, 4), 256, 0, stream>>>(u, off0_w, off0_b, off0);
  k_dwdeform<5, 5, 2, 1, 50, h16><<<dim3(256, 4), 256, 0, stream>>>(u, off0, dw0_w, a1);
  k_conv7<<<dim3(64, 7, 4), 256, 0, stream>>>(a1, offs_w, offs_b, offs);
  k_dwdeform<7, 7, 9, 3, 98, float><<<dim3(256, 4), 256, 0, stream>>>(a1, offs, dws_w, a2);
  k_g1<<<dim3(1024, 4), 256, 0, stream>>>(a2, g1_w, g1_b, a3);
  k_final<<<dim3(1024, 4), 256, 0, stream>>>(u, a3, hpre, mean, rs, p2_w, p2_b, (float*)d_out);
}

// Round 3
// 2911.761 us; speedup vs baseline: 2.1553x; 2.1553x over previous
//
#include <hip/hip_runtime.h>
#include <math.h>

#define HW 65536

typedef _Float16 h16;
typedef __attribute__((ext_vector_type(8))) _Float16 h16x8;
typedef __attribute__((ext_vector_type(2))) _Float16 h16x2;
typedef __attribute__((ext_vector_type(4))) float f32x4;

// ================= x NCHW fp32 -> NHWC f16 =================
__global__ __launch_bounds__(256) void k_x2nhwc(const float* __restrict__ x, h16* __restrict__ xh) {
  __shared__ float sT[64 * 65];
  const int b = blockIdx.y, p0 = blockIdx.x * 64, tid = threadIdx.x;
  for (int i = tid; i < 4096; i += 256) {
    int c = i >> 6, p = i & 63;
    sT[p * 65 + c] = x[((size_t)(b * 64 + c)) * HW + p0 + p];
  }
  __syncthreads();
  for (int i = tid; i < 512; i += 256) {
    int p = i >> 3, oct = i & 7;
    h16x8 v;
#pragma unroll
    for (int q = 0; q < 8; q++) v[q] = (h16)sT[p * 65 + oct * 8 + q];
    *(h16x8*)(xh + ((size_t)(b * HW + p0 + p)) * 64 + oct * 8) = v;
  }
}

// ================= weight preps =================
// [COUT][64][K] fp32 -> [K][CPAD][64] f16 (zero-pad oc)
__global__ void k_wtap(const float* __restrict__ w, h16* __restrict__ o, int COUT, int CPAD, int K) {
  int i = blockIdx.x * 256 + threadIdx.x;
  if (i >= K * CPAD * 64) return;
  int ic = i & 63, rem = i >> 6;
  int op = rem % CPAD, k = rem / CPAD;
  o[i] = (op < COUT) ? (h16)w[((size_t)op * 64 + ic) * K + k] : (h16)0.f;
}
// [64][K] fp32 -> [K][64] f16
__global__ void k_wdwp(const float* __restrict__ w, h16* __restrict__ o, int K) {
  int i = blockIdx.x * 256 + threadIdx.x;
  if (i >= K * 64) return;
  o[i] = (h16)w[(i & 63) * K + (i >> 6)];
}
__global__ void k_wcvt(const float* __restrict__ w, h16* __restrict__ o, int n) {
  int i = blockIdx.x * 256 + threadIdx.x;
  if (i < n) o[i] = (h16)w[i];
}

// ================= instance-norm stats =================
__global__ void k_stats(const float* __restrict__ ssum, const float* __restrict__ ssqs,
                        float* __restrict__ mean, float* __restrict__ rs) {
  int i = threadIdx.x;
  float m = ssum[i] * (1.f / 65536.f);
  float v = ssqs[i] * (1.f / 65536.f) - m * m;
  mean[i] = m;
  rs[i] = rsqrtf(v + 1e-5f);
}
// fold IN into p1 weights: per (b,oc)
__global__ void k_foldp1(const float* __restrict__ w, const float* __restrict__ bias,
    const float* __restrict__ mean, const float* __restrict__ rs,
    h16* __restrict__ wo, float* __restrict__ bo) {
  int t = threadIdx.x;
  int b = t >> 6, oc = t & 63;
  float a = bias[oc];
  for (int ic = 0; ic < 64; ic++) {
    float ww = w[oc * 64 + ic] * rs[b * 64 + ic];
    wo[(size_t)(b * 64 + oc) * 64 + ic] = (h16)ww;
    a -= mean[b * 64 + ic] * ww;
  }
  bo[b * 64 + oc] = a;
}

// ================= MFMA direct conv (NHWC f16) =================
// out tile per block: 8 rows x 32 x; 4 waves, wave w -> rows 2w,2w+1
template <int KW, int DIL, int PAD, int COUT, int OCG, int CS, bool STATS, bool BIAS>
__global__ __launch_bounds__(256) void k_conv(const h16* __restrict__ in,
    const h16* __restrict__ wt, const float* __restrict__ bias,
    h16* __restrict__ out, float* __restrict__ ssum, float* __restrict__ ssqs) {
  constexpr int SW = 32 + 2 * PAD;
  constexpr int N16 = 8 * SW * 8;
  __shared__ h16 sIn[8 * SW * 64];
  const int tid = threadIdx.x;
  const int wv = tid >> 6, lane = tid & 63, llo = lane & 15, lhi = lane >> 4;
  const int y0 = blockIdx.y * 8, x0 = blockIdx.x * 32, b = blockIdx.z;
  f32x4 acc[OCG][4];
#pragma unroll
  for (int o = 0; o < OCG; o++)
#pragma unroll
    for (int g = 0; g < 4; g++) acc[o][g] = f32x4{0.f, 0.f, 0.f, 0.f};
#pragma unroll 1
  for (int ki = 0; ki < KW; ++ki) {
    __syncthreads();
    for (int i = tid; i < N16; i += 256) {
      int r = i / (SW * 8);
      int rem = i - r * SW * 8;
      int xx = rem >> 3, oct = rem & 7;
      int gy = y0 - PAD + DIL * ki + r, gx = x0 - PAD + xx;
      h16x8 v = {};
      if ((unsigned)gy < 256u && (unsigned)gx < 256u)
        v = *(const h16x8*)(in + ((size_t)((b * 256 + gy) * 256 + gx)) * 64 + oct * 8);
      int byte = (((r * SW + xx) * 64 + oct * 8) << 1) ^ ((xx & 7) << 4);
      *(h16x8*)((char*)sIn + byte) = v;
    }
    __syncthreads();
#pragma unroll 1
    for (int kj = 0; kj < KW; ++kj) {
#pragma unroll
      for (int c = 0; c < 2; ++c) {
        const int koff = c * 32 + lhi * 8;
        h16x8 af[OCG];
#pragma unroll
        for (int o = 0; o < OCG; o++)
          af[o] = *(const h16x8*)(wt + (size_t)((ki * KW + kj) * (OCG * 16) + o * 16 + llo) * 64 + koff);
#pragma unroll
        for (int g = 0; g < 4; g++) {
          int row = 2 * wv + (g >> 1);
          int xl = (g & 1) * 16 + llo + DIL * kj;
          int byte = (((row * SW + xl) * 64 + koff) << 1) ^ ((xl & 7) << 4);
          h16x8 bf = *(const h16x8*)((const char*)sIn + byte);
#pragma unroll
          for (int o = 0; o < OCG; o++)
            acc[o][g] = __builtin_amdgcn_mfma_f32_16x16x32_f16(af[o], bf, acc[o][g], 0, 0, 0);
        }
      }
    }
  }
  if (STATS) {
#pragma unroll
    for (int o = 0; o < OCG; o++)
#pragma unroll
      for (int j = 0; j < 4; j++) {
        float s = 0.f, s2 = 0.f;
#pragma unroll
        for (int g = 0; g < 4; g++) { float v = acc[o][g][j]; s += v; s2 += v * v; }
#pragma unroll
        for (int m = 1; m < 16; m <<= 1) { s += __shfl_xor(s, m); s2 += __shfl_xor(s2, m); }
        if (llo == 0) {
          int oc = o * 16 + lhi * 4 + j;
          atomicAdd(&ssum[b * 64 + oc], s);
          atomicAdd(&ssqs[b * 64 + oc], s2);
        }
      }
  }
#pragma unroll
  for (int o = 0; o < OCG; o++)
#pragma unroll
    for (int g = 0; g < 4; g++) {
      int row = 2 * wv + (g >> 1), xg = (g & 1) * 16 + llo;
      size_t pb = ((size_t)((b * 256 + y0 + row) * 256 + x0 + xg)) * CS;
#pragma unroll
      for (int jp = 0; jp < 2; jp++) {
        int oc = o * 16 + lhi * 4 + jp * 2;
        if (oc < COUT) {
          float v0 = acc[o][g][jp * 2], v1 = acc[o][g][jp * 2 + 1];
          if (BIAS) { v0 += bias[oc]; v1 += bias[oc + 1]; }
          h16x2 pk = {(h16)v0, (h16)v1};
          *(h16x2*)(out + pb + oc) = pk;
        }
      }
    }
}

// ================= MFMA 1x1 GEMM (NHWC f16) =================
// EPI 0: p1 (per-b folded W + GELU -> f16); 1: g1 (+bias -> f16);
// EPI 2: final (B = u*a3, +bias +IN(hpre) residual, LeakyReLU -> NCHW fp32)
template <int EPI>
__global__ __launch_bounds__(256) void k_pw(const h16* __restrict__ inA,
    const h16* __restrict__ inB2, const h16* __restrict__ wt,
    const float* __restrict__ bias, const h16* __restrict__ hpre,
    const float* __restrict__ mean, const float* __restrict__ rs,
    h16* __restrict__ outh, float* __restrict__ outf) {
  const int b = blockIdx.y;
  const int tid = threadIdx.x, lane = tid & 63, wv = tid >> 6, llo = lane & 15, lhi = lane >> 4;
  const int pixloc = blockIdx.x * 256 + wv * 64;
  const size_t pix0 = (size_t)b * HW + pixloc;
  const h16* W = wt + (EPI == 0 ? b * 4096 : 0);
  f32x4 acc[4][4];
#pragma unroll
  for (int o = 0; o < 4; o++)
#pragma unroll
    for (int g = 0; g < 4; g++) acc[o][g] = f32x4{0.f, 0.f, 0.f, 0.f};
#pragma unroll
  for (int c = 0; c < 2; c++) {
    const int koff = c * 32 + lhi * 8;
    h16x8 af[4];
#pragma unroll
    for (int o = 0; o < 4; o++)
      af[o] = *(const h16x8*)(W + (o * 16 + llo) * 64 + koff);
#pragma unroll
    for (int g = 0; g < 4; g++) {
      size_t pa = (pix0 + g * 16 + llo) * 64 + koff;
      h16x8 bf = *(const h16x8*)(inA + pa);
      if (EPI == 2) { h16x8 b2 = *(const h16x8*)(inB2 + pa); bf = bf * b2; }
#pragma unroll
      for (int o = 0; o < 4; o++)
        acc[o][g] = __builtin_amdgcn_mfma_f32_16x16x32_f16(af[o], bf, acc[o][g], 0, 0, 0);
    }
  }
#pragma unroll
  for (int o = 0; o < 4; o++)
#pragma unroll
    for (int g = 0; g < 4; g++) {
      int pl = pixloc + g * 16 + llo;
      size_t pix = (size_t)b * HW + pl;
      if (EPI == 2) {
#pragma unroll
        for (int j = 0; j < 4; j++) {
          int oc = o * 16 + lhi * 4 + j;
          float t = acc[o][g][j] + bias[oc];
          float hp = (float)hpre[pix * 64 + oc];
          t += (hp - mean[b * 64 + oc]) * rs[b * 64 + oc];
          outf[(size_t)(b * 64 + oc) * HW + pl] = (t >= 0.f) ? t : 0.2f * t;
        }
      } else {
#pragma unroll
        for (int jp = 0; jp < 2; jp++) {
          int oc = o * 16 + lhi * 4 + jp * 2;
          float v0 = acc[o][g][jp * 2], v1 = acc[o][g][jp * 2 + 1];
          if (EPI == 0) {
            v0 += bias[b * 64 + oc]; v1 += bias[b * 64 + oc + 1];
            v0 = 0.5f * v0 * (1.f + erff(v0 * 0.70710678f));
            v1 = 0.5f * v1 * (1.f + erff(v1 * 0.70710678f));
          } else {
            v0 += bias[oc]; v1 += bias[oc + 1];
          }
          h16x2 pk = {(h16)v0, (h16)v1};
          *(h16x2*)(outh + pix * 64 + oc) = pk;
        }
      }
    }
}

// ================= deformable depthwise conv (NHWC f16, lane=pixel) =================
template <int KH, int KW, int PADT, int DILT, int NOFF>
__global__ __launch_bounds__(256) void k_dw(const h16* __restrict__ in,
    const h16* __restrict__ off, const h16* __restrict__ wk, h16* __restrict__ out) {
  __shared__ h16 sW[KH * KW * 64];
  const int b = blockIdx.y, y = blockIdx.x, x = threadIdx.x;
  for (int i = threadIdx.x; i < KH * KW * 64; i += 256) sW[i] = wk[i];
  __syncthreads();
  const h16* ib = in + (size_t)b * HW * 64;
  const h16* ob = off + ((size_t)b * HW + y * 256 + x) * NOFF;
  float acc[64];
#pragma unroll
  for (int j = 0; j < 64; j++) acc[j] = 0.f;
  int ki = 0, kj = 0;
#pragma unroll 1
  for (int k = 0; k < KH * KW; k++) {
    h16x2 d = *(const h16x2*)(ob + 2 * k);
    float py = (float)(y - PADT + DILT * ki) + (float)d.x;
    float px = (float)(x - PADT + DILT * kj) + (float)d.y;
    float y0f = floorf(py), x0f = floorf(px);
    float fy = py - y0f, fx = px - x0f;
    int iy0 = (int)y0f, ix0 = (int)x0f;
    bool vy0 = (iy0 >= 0) && (iy0 <= 255), vy1 = (iy0 >= -1) && (iy0 <= 254);
    bool vx0 = (ix0 >= 0) && (ix0 <= 255), vx1 = (ix0 >= -1) && (ix0 <= 254);
    float w00 = (1.f - fy) * (1.f - fx) * ((vy0 && vx0) ? 1.f : 0.f);
    float w01 = (1.f - fy) * fx * ((vy0 && vx1) ? 1.f : 0.f);
    float w10 = fy * (1.f - fx) * ((vy1 && vx0) ? 1.f : 0.f);
    float w11 = fy * fx * ((vy1 && vx1) ? 1.f : 0.f);
    int cy0 = min(max(iy0, 0), 255), cy1 = min(max(iy0 + 1, 0), 255);
    int cx0 = min(max(ix0, 0), 255), cx1 = min(max(ix0 + 1, 0), 255);
    const h16* p00 = ib + (size_t)(cy0 * 256 + cx0) * 64;
    const h16* p01 = ib + (size_t)(cy0 * 256 + cx1) * 64;
    const h16* p10 = ib + (size_t)(cy1 * 256 + cx0) * 64;
    const h16* p11 = ib + (size_t)(cy1 * 256 + cx1) * 64;
    h16 h00 = (h16)w00, h01 = (h16)w01, h10 = (h16)w10, h11 = (h16)w11;
    h16x2 W00 = {h00, h00}, W01 = {h01, h01}, W10 = {h10, h10}, W11 = {h11, h11};
#pragma unroll
    for (int oct = 0; oct < 8; ++oct) {
      h16x8 v00 = *(const h16x8*)(p00 + oct * 8);
      h16x8 v01 = *(const h16x8*)(p01 + oct * 8);
      h16x8 v10 = *(const h16x8*)(p10 + oct * 8);
      h16x8 v11 = *(const h16x8*)(p11 + oct * 8);
#pragma unroll
      for (int t = 0; t < 4; t++) {
        h16x2 a = {v00[2 * t], v00[2 * t + 1]};
        h16x2 s = a * W00;
        h16x2 b1 = {v01[2 * t], v01[2 * t + 1]}; s += b1 * W01;
        h16x2 c1 = {v10[2 * t], v10[2 * t + 1]}; s += c1 * W10;
        h16x2 d1 = {v11[2 * t], v11[2 * t + 1]}; s += d1 * W11;
        h16x2 wc = *(const h16x2*)(&sW[k * 64 + oct * 8 + 2 * t]);
        s = s * wc;
        acc[oct * 8 + 2 * t] += (float)s.x;
        acc[oct * 8 + 2 * t + 1] += (float)s.y;
      }
    }
    kj++; if (kj == KW) { kj = 0; ki++; }
  }
  size_t pb = ((size_t)b * HW + y * 256 + x) * 64;
#pragma unroll
  for (int oct = 0; oct < 8; oct++) {
    h16x8 v;
#pragma unroll
    for (int q = 0; q < 8; q++) v[q] = (h16)acc[oct * 8 + q];
    *(h16x8*)(out + pb + oct * 8) = v;
  }
}

extern "C" void kernel_launch(void* const* d_in, const int* in_sizes, int n_in,
                              void* d_out, int out_size, void* d_ws, size_t ws_size,
                              hipStream_t stream) {
  const float* x      = (const float*)d_in[0];
  const float* conv_w = (const float*)d_in[1];
  const float* p1_w   = (const float*)d_in[2];
  const float* p1_b   = (const float*)d_in[3];
  const float* off0_w = (const float*)d_in[4];
  const float* off0_b = (const float*)d_in[5];
  const float* dw0_w  = (const float*)d_in[6];
  const float* offs_w = (const float*)d_in[7];
  const float* offs_b = (const float*)d_in[8];
  const float* dws_w  = (const float*)d_in[9];
  const float* g1_w   = (const float*)d_in[10];
  const float* g1_b   = (const float*)d_in[11];
  const float* p2_w   = (const float*)d_in[12];
  const float* p2_b   = (const float*)d_in[13];

  float* fb   = (float*)d_ws;
  float* ssum = fb;            // 256
  float* ssqs = fb + 256;      // 256
  float* mean = fb + 512;      // 256
  float* rs   = fb + 768;      // 256
  float* p1bf = fb + 1024;     // 256
  h16* hb   = (h16*)((char*)d_ws + 8192);
  h16* xh   = hb;                          // 16,777,216 (reused as u)
  h16* hpre = xh + (size_t)16777216;       // 16,777,216
  h16* a1   = hpre + (size_t)16777216;     // 16,777,216 (reused as a3)
  h16* offs = a1 + (size_t)16777216;       // 25,690,112 (off0 shares start)
  h16* wbuf = offs + (size_t)25690112;
  h16* wc3  = wbuf;                        // 9*64*64   = 36,864
  h16* wc5  = wc3 + 36864;                 // 25*64*64  = 102,400
  h16* wc7  = wc5 + 102400;                // 49*112*64 = 351,232
  h16* wdw5 = wc7 + 351232;                // 1,600
  h16* wdw7 = wdw5 + 1600;                 // 3,136
  h16* wg1  = wdw7 + 3136;                 // 4,096
  h16* wp2  = wg1 + 4096;                  // 4,096
  h16* wp1f = wp2 + 4096;                  // 16,384
  h16* u    = xh;
  h16* off0 = offs;
  h16* a3   = a1;
  h16* a2   = (h16*)d_out;                 // d_out as f16 scratch (fully rewritten later)

  hipMemsetAsync(ssum, 0, 512 * sizeof(float), stream);

  k_x2nhwc<<<dim3(1024, 4), 256, 0, stream>>>(x, xh);
  k_wtap<<<144, 256, 0, stream>>>(conv_w, wc3, 64, 64, 9);
  k_wtap<<<400, 256, 0, stream>>>(off0_w, wc5, 50, 64, 25);
  k_wtap<<<1372, 256, 0, stream>>>(offs_w, wc7, 98, 112, 49);
  k_wdwp<<<7, 256, 0, stream>>>(dw0_w, wdw5, 25);
  k_wdwp<<<13, 256, 0, stream>>>(dws_w, wdw7, 49);
  k_wcvt<<<16, 256, 0, stream>>>(g1_w, wg1, 4096);
  k_wcvt<<<16, 256, 0, stream>>>(p2_w, wp2, 4096);

  k_conv<3, 1, 1, 64, 4, 64, true, false><<<dim3(8, 32, 4), 256, 0, stream>>>(
      xh, wc3, nullptr, hpre, ssum, ssqs);
  k_stats<<<1, 256, 0, stream>>>(ssum, ssqs, mean, rs);
  k_foldp1<<<1, 256, 0, stream>>>(p1_w, p1_b, mean, rs, wp1f, p1bf);
  k_pw<0><<<dim3(256, 4), 256, 0, stream>>>(hpre, nullptr, wp1f, p1bf,
      nullptr, nullptr, nullptr, u, nullptr);
  k_conv<5, 1, 2, 50, 4, 50, false, true><<<dim3(8, 32, 4), 256, 0, stream>>>(
      u, wc5, off0_b, off0, nullptr, nullptr);
  k_dw<5, 5, 2, 1, 50><<<dim3(256, 4), 256, 0, stream>>>(u, off0, wdw5, a1);
  k_conv<7, 3, 9, 98, 7, 98, false, true><<<dim3(8, 32, 4), 256, 0, stream>>>(
      a1, wc7, offs_b, offs, nullptr, nullptr);
  k_dw<7, 7, 9, 3, 98><<<dim3(256, 4), 256, 0, stream>>>(a1, offs, wdw7, a2);
  k_pw<1><<<dim3(256, 4), 256, 0, stream>>>(a2, nullptr, wg1, g1_b,
      nullptr, nullptr, nullptr, a3, nullptr);
  k_pw<2><<<dim3(256, 4), 256, 0, stream>>>(u, a3, wp2, p2_b,
      hpre, mean, rs, nullptr, (float*)d_out);
}

// Round 5
// 1337.824 us; speedup vs baseline: 4.6911x; 2.1765x over previous
//
#include <hip/hip_runtime.h>
#include <math.h>

#define HW 65536

typedef _Float16 h16;
typedef __attribute__((ext_vector_type(8))) _Float16 h16x8;
typedef __attribute__((ext_vector_type(2))) _Float16 h16x2;
typedef __attribute__((ext_vector_type(4))) float f32x4;

// ================= x NCHW fp32 -> NHWC f16 =================
__global__ __launch_bounds__(256) void k_x2nhwc(const float* __restrict__ x, h16* __restrict__ xh) {
  __shared__ float sT[64 * 65];
  const int b = blockIdx.y, p0 = blockIdx.x * 64, tid = threadIdx.x;
  for (int i = tid; i < 4096; i += 256) {
    int c = i >> 6, p = i & 63;
    sT[p * 65 + c] = x[((size_t)(b * 64 + c)) * HW + p0 + p];
  }
  __syncthreads();
  for (int i = tid; i < 512; i += 256) {
    int p = i >> 3, oct = i & 7;
    h16x8 v;
#pragma unroll
    for (int q = 0; q < 8; q++) v[q] = (h16)sT[p * 65 + oct * 8 + q];
    *(h16x8*)(xh + ((size_t)(b * HW + p0 + p)) * 64 + oct * 8) = v;
  }
}

// ================= weight preps =================
__global__ void k_wtap(const float* __restrict__ w, h16* __restrict__ o, int COUT, int CPAD, int K) {
  int i = blockIdx.x * 256 + threadIdx.x;
  if (i >= K * CPAD * 64) return;
  int ic = i & 63, rem = i >> 6;
  int op = rem % CPAD, k = rem / CPAD;
  o[i] = (op < COUT) ? (h16)w[((size_t)op * 64 + ic) * K + k] : (h16)0.f;
}
__global__ void k_wdwp(const float* __restrict__ w, h16* __restrict__ o, int K) {
  int i = blockIdx.x * 256 + threadIdx.x;
  if (i >= K * 64) return;
  o[i] = (h16)w[(i & 63) * K + (i >> 6)];
}
__global__ void k_wcvt(const float* __restrict__ w, h16* __restrict__ o, int n) {
  int i = blockIdx.x * 256 + threadIdx.x;
  if (i < n) o[i] = (h16)w[i];
}

// ================= instance-norm stats =================
__global__ void k_stats(const float* __restrict__ ssum, const float* __restrict__ ssqs,
                        float* __restrict__ mean, float* __restrict__ rs) {
  int i = threadIdx.x;
  float m = ssum[i] * (1.f / 65536.f);
  float v = ssqs[i] * (1.f / 65536.f) - m * m;
  mean[i] = m;
  rs[i] = rsqrtf(v + 1e-5f);
}
__global__ void k_foldp1(const float* __restrict__ w, const float* __restrict__ bias,
    const float* __restrict__ mean, const float* __restrict__ rs,
    h16* __restrict__ wo, float* __restrict__ bo) {
  int t = threadIdx.x;
  int b = t >> 6, oc = t & 63;
  float a = bias[oc];
  for (int ic = 0; ic < 64; ic++) {
    float ww = w[oc * 64 + ic] * rs[b * 64 + ic];
    wo[(size_t)(b * 64 + oc) * 64 + ic] = (h16)ww;
    a -= mean[b * 64 + ic] * ww;
  }
  bo[b * 64 + oc] = a;
}

// ================= MFMA direct conv (NHWC f16) =================
template <int KW, int DIL, int PAD, int COUT, int OCG, int CS, bool STATS, bool BIAS>
__global__ __launch_bounds__(256) void k_conv(const h16* __restrict__ in,
    const h16* __restrict__ wt, const float* __restrict__ bias,
    h16* __restrict__ out, float* __restrict__ ssum, float* __restrict__ ssqs) {
  constexpr int SW = 32 + 2 * PAD;
  constexpr int N16 = 8 * SW * 8;
  __shared__ h16 sIn[8 * SW * 64];
  const int tid = threadIdx.x;
  const int wv = tid >> 6, lane = tid & 63, llo = lane & 15, lhi = lane >> 4;
  const int y0 = blockIdx.y * 8, x0 = blockIdx.x * 32, b = blockIdx.z;
  f32x4 acc[OCG][4];
#pragma unroll
  for (int o = 0; o < OCG; o++)
#pragma unroll
    for (int g = 0; g < 4; g++) acc[o][g] = f32x4{0.f, 0.f, 0.f, 0.f};
#pragma unroll 1
  for (int ki = 0; ki < KW; ++ki) {
    __syncthreads();
    for (int i = tid; i < N16; i += 256) {
      int r = i / (SW * 8);
      int rem = i - r * SW * 8;
      int xx = rem >> 3, oct = rem & 7;
      int gy = y0 - PAD + DIL * ki + r, gx = x0 - PAD + xx;
      h16x8 v = {};
      if ((unsigned)gy < 256u && (unsigned)gx < 256u)
        v = *(const h16x8*)(in + ((size_t)((b * 256 + gy) * 256 + gx)) * 64 + oct * 8);
      int byte = (((r * SW + xx) * 64 + oct * 8) << 1) ^ ((xx & 7) << 4);
      *(h16x8*)((char*)sIn + byte) = v;
    }
    __syncthreads();
#pragma unroll 1
    for (int kj = 0; kj < KW; ++kj) {
#pragma unroll
      for (int c = 0; c < 2; ++c) {
        const int koff = c * 32 + lhi * 8;
        h16x8 af[OCG];
#pragma unroll
        for (int o = 0; o < OCG; o++)
          af[o] = *(const h16x8*)(wt + (size_t)((ki * KW + kj) * (OCG * 16) + o * 16 + llo) * 64 + koff);
#pragma unroll
        for (int g = 0; g < 4; g++) {
          int row = 2 * wv + (g >> 1);
          int xl = (g & 1) * 16 + llo + DIL * kj;
          int byte = (((row * SW + xl) * 64 + koff) << 1) ^ ((xl & 7) << 4);
          h16x8 bf = *(const h16x8*)((const char*)sIn + byte);
#pragma unroll
          for (int o = 0; o < OCG; o++)
            acc[o][g] = __builtin_amdgcn_mfma_f32_16x16x32_f16(af[o], bf, acc[o][g], 0, 0, 0);
        }
      }
    }
  }
  if (STATS) {
#pragma unroll
    for (int o = 0; o < OCG; o++)
#pragma unroll
      for (int j = 0; j < 4; j++) {
        float s = 0.f, s2 = 0.f;
#pragma unroll
        for (int g = 0; g < 4; g++) { float v = acc[o][g][j]; s += v; s2 += v * v; }
#pragma unroll
        for (int m = 1; m < 16; m <<= 1) { s += __shfl_xor(s, m); s2 += __shfl_xor(s2, m); }
        if (llo == 0) {
          int oc = o * 16 + lhi * 4 + j;
          atomicAdd(&ssum[b * 64 + oc], s);
          atomicAdd(&ssqs[b * 64 + oc], s2);
        }
      }
  }
#pragma unroll
  for (int o = 0; o < OCG; o++)
#pragma unroll
    for (int g = 0; g < 4; g++) {
      int row = 2 * wv + (g >> 1), xg = (g & 1) * 16 + llo;
      size_t pb = ((size_t)((b * 256 + y0 + row) * 256 + x0 + xg)) * CS;
#pragma unroll
      for (int jp = 0; jp < 2; jp++) {
        int oc = o * 16 + lhi * 4 + jp * 2;
        if (oc < COUT) {
          float v0 = acc[o][g][jp * 2], v1 = acc[o][g][jp * 2 + 1];
          if (BIAS) { v0 += bias[oc]; v1 += bias[oc + 1]; }
          h16x2 pk = {(h16)v0, (h16)v1};
          *(h16x2*)(out + pb + oc) = pk;
        }
      }
    }
}

// ================= MFMA 1x1 GEMM (NHWC f16) =================
template <int EPI>
__global__ __launch_bounds__(256) void k_pw(const h16* __restrict__ inA,
    const h16* __restrict__ inB2, const h16* __restrict__ wt,
    const float* __restrict__ bias, const h16* __restrict__ hpre,
    const float* __restrict__ mean, const float* __restrict__ rs,
    h16* __restrict__ outh, float* __restrict__ outf) {
  const int b = blockIdx.y;
  const int tid = threadIdx.x, lane = tid & 63, wv = tid >> 6, llo = lane & 15, lhi = lane >> 4;
  const int pixloc = blockIdx.x * 256 + wv * 64;
  const size_t pix0 = (size_t)b * HW + pixloc;
  const h16* W = wt + (EPI == 0 ? b * 4096 : 0);
  f32x4 acc[4][4];
#pragma unroll
  for (int o = 0; o < 4; o++)
#pragma unroll
    for (int g = 0; g < 4; g++) acc[o][g] = f32x4{0.f, 0.f, 0.f, 0.f};
#pragma unroll
  for (int c = 0; c < 2; c++) {
    const int koff = c * 32 + lhi * 8;
    h16x8 af[4];
#pragma unroll
    for (int o = 0; o < 4; o++)
      af[o] = *(const h16x8*)(W + (o * 16 + llo) * 64 + koff);
#pragma unroll
    for (int g = 0; g < 4; g++) {
      size_t pa = (pix0 + g * 16 + llo) * 64 + koff;
      h16x8 bf = *(const h16x8*)(inA + pa);
      if (EPI == 2) { h16x8 b2 = *(const h16x8*)(inB2 + pa); bf = bf * b2; }
#pragma unroll
      for (int o = 0; o < 4; o++)
        acc[o][g] = __builtin_amdgcn_mfma_f32_16x16x32_f16(af[o], bf, acc[o][g], 0, 0, 0);
    }
  }
#pragma unroll
  for (int o = 0; o < 4; o++)
#pragma unroll
    for (int g = 0; g < 4; g++) {
      int pl = pixloc + g * 16 + llo;
      size_t pix = (size_t)b * HW + pl;
      if (EPI == 2) {
#pragma unroll
        for (int j = 0; j < 4; j++) {
          int oc = o * 16 + lhi * 4 + j;
          float t = acc[o][g][j] + bias[oc];
          float hp = (float)hpre[pix * 64 + oc];
          t += (hp - mean[b * 64 + oc]) * rs[b * 64 + oc];
          outf[(size_t)(b * 64 + oc) * HW + pl] = (t >= 0.f) ? t : 0.2f * t;
        }
      } else {
#pragma unroll
        for (int jp = 0; jp < 2; jp++) {
          int oc = o * 16 + lhi * 4 + jp * 2;
          float v0 = acc[o][g][jp * 2], v1 = acc[o][g][jp * 2 + 1];
          if (EPI == 0) {
            v0 += bias[b * 64 + oc]; v1 += bias[b * 64 + oc + 1];
            v0 = 0.5f * v0 * (1.f + erff(v0 * 0.70710678f));
            v1 = 0.5f * v1 * (1.f + erff(v1 * 0.70710678f));
          } else {
            v0 += bias[oc]; v1 += bias[oc + 1];
          }
          h16x2 pk = {(h16)v0, (h16)v1};
          *(h16x2*)(outh + pix * 64 + oc) = pk;
        }
      }
    }
}

// ================= deformable depthwise conv =================
// lane = (pixel, channel-oct): 8 lanes per pixel -> contiguous 128B gathers.
// 1D grid, XCD-banded swizzle: fid&7 = XCD owns y-band [32*xcd, 32*xcd+32).
template <int KH, int KW, int PADT, int DILT, int NOFF>
__global__ __launch_bounds__(256) void k_dw(const h16* __restrict__ in,
    const h16* __restrict__ off, const h16* __restrict__ wk, h16* __restrict__ out) {
  __shared__ h16 sW[KH * KW * 64];
  for (int i = threadIdx.x; i < KH * KW * 64; i += 256) sW[i] = wk[i];
  __syncthreads();
  const int fid = blockIdx.x;
  const int xcd = fid & 7, idx = fid >> 3;
  const int b = idx >> 8, yb = (idx >> 3) & 31, xs = idx & 7;
  const int y = xcd * 32 + yb;
  const int wv = threadIdx.x >> 6, lane = threadIdx.x & 63;
  const int pid = wv * 8 + (lane >> 3);   // 0..31 pixel within 32-px segment
  const int oct = lane & 7;
  const int x = xs * 32 + pid;
  const h16* ib = in + (size_t)b * HW * 64 + oct * 8;
  const h16* ob = off + ((size_t)b * HW + y * 256 + x) * NOFF;
  const h16* wko = sW + oct * 8;
  float accf[8];
#pragma unroll
  for (int q = 0; q < 8; q++) accf[q] = 0.f;
  int ki = 0, kj = 0;
#pragma unroll 1
  for (int k = 0; k < KH * KW; k++) {
    h16x2 d = *(const h16x2*)(ob + 2 * k);
    float py = (float)(y - PADT + DILT * ki) + (float)d.x;
    float px = (float)(x - PADT + DILT * kj) + (float)d.y;
    float y0f = floorf(py), x0f = floorf(px);
    float fy = py - y0f, fx = px - x0f;
    int iy0 = (int)y0f, ix0 = (int)x0f;
    bool vy0 = (iy0 >= 0) && (iy0 <= 255), vy1 = (iy0 >= -1) && (iy0 <= 254);
    bool vx0 = (ix0 >= 0) && (ix0 <= 255), vx1 = (ix0 >= -1) && (ix0 <= 254);
    float w00 = (1.f - fy) * (1.f - fx) * ((vy0 && vx0) ? 1.f : 0.f);
    float w01 = (1.f - fy) * fx * ((vy0 && vx1) ? 1.f : 0.f);
    float w10 = fy * (1.f - fx) * ((vy1 && vx0) ? 1.f : 0.f);
    float w11 = fy * fx * ((vy1 && vx1) ? 1.f : 0.f);
    int cy0 = min(max(iy0, 0), 255), cy1 = min(max(iy0 + 1, 0), 255);
    int cx0 = min(max(ix0, 0), 255), cx1 = min(max(ix0 + 1, 0), 255);
    h16x8 v00 = *(const h16x8*)(ib + (size_t)(cy0 * 256 + cx0) * 64);
    h16x8 v01 = *(const h16x8*)(ib + (size_t)(cy0 * 256 + cx1) * 64);
    h16x8 v10 = *(const h16x8*)(ib + (size_t)(cy1 * 256 + cx0) * 64);
    h16x8 v11 = *(const h16x8*)(ib + (size_t)(cy1 * 256 + cx1) * 64);
    h16 h00 = (h16)w00, h01 = (h16)w01, h10 = (h16)w10, h11 = (h16)w11;
    h16x2 W00 = {h00, h00}, W01 = {h01, h01}, W10 = {h10, h10}, W11 = {h11, h11};
#pragma unroll
    for (int t = 0; t < 4; t++) {
      h16x2 a = {v00[2 * t], v00[2 * t + 1]};
      h16x2 s = a * W00;
      h16x2 b1 = {v01[2 * t], v01[2 * t + 1]}; s += b1 * W01;
      h16x2 c1 = {v10[2 * t], v10[2 * t + 1]}; s += c1 * W10;
      h16x2 d1 = {v11[2 * t], v11[2 * t + 1]}; s += d1 * W11;
      h16x2 wc = *(const h16x2*)(&wko[k * 64 + 2 * t]);
      s = s * wc;
      accf[2 * t] += (float)s.x;
      accf[2 * t + 1] += (float)s.y;
    }
    kj++; if (kj == KW) { kj = 0; ki++; }
  }
  h16x8 v;
#pragma unroll
  for (int q = 0; q < 8; q++) v[q] = (h16)accf[q];
  *(h16x8*)(out + ((size_t)b * HW + y * 256 + x) * 64 + oct * 8) = v;
}

extern "C" void kernel_launch(void* const* d_in, const int* in_sizes, int n_in,
                              void* d_out, int out_size, void* d_ws, size_t ws_size,
                              hipStream_t stream) {
  const float* x      = (const float*)d_in[0];
  const float* conv_w = (const float*)d_in[1];
  const float* p1_w   = (const float*)d_in[2];
  const float* p1_b   = (const float*)d_in[3];
  const float* off0_w = (const float*)d_in[4];
  const float* off0_b = (const float*)d_in[5];
  const float* dw0_w  = (const float*)d_in[6];
  const float* offs_w = (const float*)d_in[7];
  const float* offs_b = (const float*)d_in[8];
  const float* dws_w  = (const float*)d_in[9];
  const float* g1_w   = (const float*)d_in[10];
  const float* g1_b   = (const float*)d_in[11];
  const float* p2_w   = (const float*)d_in[12];
  const float* p2_b   = (const float*)d_in[13];

  float* fb   = (float*)d_ws;
  float* ssum = fb;            // 256
  float* ssqs = fb + 256;      // 256
  float* mean = fb + 512;      // 256
  float* rs   = fb + 768;      // 256
  float* p1bf = fb + 1024;     // 256
  h16* hb   = (h16*)((char*)d_ws + 8192);
  h16* xh   = hb;                          // 16,777,216 (reused as u)
  h16* hpre = xh + (size_t)16777216;
  h16* a1   = hpre + (size_t)16777216;     // (reused as a3)
  h16* offs = a1 + (size_t)16777216;       // 25,690,112 (off0 shares start)
  h16* wbuf = offs + (size_t)25690112;
  h16* wc3  = wbuf;
  h16* wc5  = wc3 + 36864;
  h16* wc7  = wc5 + 102400;
  h16* wdw5 = wc7 + 351232;
  h16* wdw7 = wdw5 + 1600;
  h16* wg1  = wdw7 + 3136;
  h16* wp2  = wg1 + 4096;
  h16* wp1f = wp2 + 4096;
  h16* u    = xh;
  h16* off0 = offs;
  h16* a3   = a1;
  h16* a2   = (h16*)d_out;

  hipMemsetAsync(ssum, 0, 512 * sizeof(float), stream);

  k_x2nhwc<<<dim3(1024, 4), 256, 0, stream>>>(x, xh);
  k_wtap<<<144, 256, 0, stream>>>(conv_w, wc3, 64, 64, 9);
  k_wtap<<<400, 256, 0, stream>>>(off0_w, wc5, 50, 64, 25);
  k_wtap<<<1372, 256, 0, stream>>>(offs_w, wc7, 98, 112, 49);
  k_wdwp<<<7, 256, 0, stream>>>(dw0_w, wdw5, 25);
  k_wdwp<<<13, 256, 0, stream>>>(dws_w, wdw7, 49);
  k_wcvt<<<16, 256, 0, stream>>>(g1_w, wg1, 4096);
  k_wcvt<<<16, 256, 0, stream>>>(p2_w, wp2, 4096);

  k_conv<3, 1, 1, 64, 4, 64, true, false><<<dim3(8, 32, 4), 256, 0, stream>>>(
      xh, wc3, nullptr, hpre, ssum, ssqs);
  k_stats<<<1, 256, 0, stream>>>(ssum, ssqs, mean, rs);
  k_foldp1<<<1, 256, 0, stream>>>(p1_w, p1_b, mean, rs, wp1f, p1bf);
  k_pw<0><<<dim3(256, 4), 256, 0, stream>>>(hpre, nullptr, wp1f, p1bf,
      nullptr, nullptr, nullptr, u, nullptr);
  k_conv<5, 1, 2, 50, 4, 50, false, true><<<dim3(8, 32, 4), 256, 0, stream>>>(
      u, wc5, off0_b, off0, nullptr, nullptr);
  k_dw<5, 5, 2, 1, 50><<<dim3(8192), 256, 0, stream>>>(u, off0, wdw5, a1);
  k_conv<7, 3, 9, 98, 7, 98, false, true><<<dim3(8, 32, 4), 256, 0, stream>>>(
      a1, wc7, offs_b, offs, nullptr, nullptr);
  k_dw<7, 7, 9, 3, 98><<<dim3(8192), 256, 0, stream>>>(a1, offs, wdw7, a2);
  k_pw<1><<<dim3(256, 4), 256, 0, stream>>>(a2, nullptr, wg1, g1_b,
      nullptr, nullptr, nullptr, a3, nullptr);
  k_pw<2><<<dim3(256, 4), 256, 0, stream>>>(u, a3, wp2, p2_b,
      hpre, mean, rs, nullptr, (float*)d_out);
}